// Round 8
// baseline (338.865 us; speedup 1.0000x reference)
//
#include <hip/hip_runtime.h>

// ITA Self-Attention QAT — round 8 (barrier-free L2-direct attention)
// B=8, N=1024, E=768, P=768, H=12, D=64
//
// vs round 7 (150.7us, attn 76us @ MfmaUtil 20 / VALU 41 / Occ 34): attn was
// barrier-serialized (64 __syncthreads/block around 8-16 MFMA each). K+V are
// L2-resident per XCD (bh%8 stable, 12 bh x 256KB = 3MB < 4MB L2), so LDS
// staging is pure overhead (common-mistake #7). New attn:
//  - NO __syncthreads at all; waves fully independent
//  - K/V MFMA fragments read direct from global (16B/lane, L2-hot)
//  - V frags loaded BEFORE softmax+lgkmcnt(0) so latency hides under VALU
//  - only LDS: 1.25KB wave-private P transpose buffer (in-order, lgkm only)
// Numerics bit-identical to round 7 (same MFMA order, same ldexpf/f2h path).
// GEMMs + prolog unchanged from round 7.

typedef unsigned short u16;
typedef __attribute__((ext_vector_type(8))) short short8;
typedef __attribute__((ext_vector_type(8))) _Float16 half8;
typedef __attribute__((ext_vector_type(4))) float f32x4;

#define LOG2E_F 1.4426950408889634f

static __device__ __forceinline__ half8 s2h(short8 s) {
  union { short8 s; half8 h; } u; u.s = s; return u.h;
}
static __device__ __forceinline__ f32x4 mfma16(short8 a, short8 b, f32x4 c) {
  return __builtin_amdgcn_mfma_f32_16x16x32_f16(s2h(a), s2h(b), c, 0, 0, 0);
}
static __device__ __forceinline__ u16 f2h(float f) {
  union { _Float16 h; u16 u; } v; v.h = (_Float16)f; return v.u;
}
static __device__ __forceinline__ void gload16(const void* g, void* l) {
  __builtin_amdgcn_global_load_lds(
      (const __attribute__((address_space(1))) void*)g,
      (__attribute__((address_space(3))) void*)l, 16, 0, 0);
}

// ---------------- amax reduction ----------------
__global__ __launch_bounds__(256) void amax_part_kernel(
    const float4* __restrict__ x, float* __restrict__ part, int n4) {
  float m = 0.f;
  int i = blockIdx.x * 256 + threadIdx.x;
  const int stride = gridDim.x * 256;
  for (; i < n4; i += stride) {
    float4 v = x[i];
    m = fmaxf(m, fmaxf(fmaxf(fabsf(v.x), fabsf(v.y)),
                       fmaxf(fabsf(v.z), fabsf(v.w))));
  }
  #pragma unroll
  for (int o = 1; o < 64; o <<= 1) m = fmaxf(m, __shfl_xor(m, o));
  __shared__ float sw[4];
  if ((threadIdx.x & 63) == 0) sw[threadIdx.x >> 6] = m;
  __syncthreads();
  if (threadIdx.x == 0)
    part[blockIdx.x] = fmaxf(fmaxf(sw[0], sw[1]), fmaxf(sw[2], sw[3]));
}

__global__ __launch_bounds__(256) void amax_fin_kernel(
    const float* __restrict__ part, double* __restrict__ dsc,
    float* __restrict__ dscf) {
  const int t = threadIdx.x;
  float m = fmaxf(fmaxf(part[t], part[t + 256]),
                  fmaxf(part[t + 512], part[t + 768]));
  #pragma unroll
  for (int o = 1; o < 64; o <<= 1) m = fmaxf(m, __shfl_xor(m, o));
  __shared__ float sw[4];
  if ((t & 63) == 0) sw[t >> 6] = m;
  __syncthreads();
  if (t == 0) {
    double sd = (double)(fmaxf(fmaxf(sw[0], sw[1]), fmaxf(sw[2], sw[3]))) / 127.0;
    if (sd < 1e-8) sd = 1e-8;
    dsc[0] = sd;
    dsc[1] = 1.0 / sd;
    dscf[0] = (float)sd;
  }
}

// ---------------- quantize: xq = clip(rint(x/s),-128,127), exact in f16 -----
__global__ __launch_bounds__(256) void quant_kernel(
    const float4* __restrict__ x, u16* __restrict__ xq,
    const double* __restrict__ dsc, int n4) {
  const double rinv = dsc[1];
  int i = blockIdx.x * 256 + threadIdx.x;
  const int stride = gridDim.x * 256;
  for (; i < n4; i += stride) {
    float4 v = x[i];
    ushort4 u;
    u.x = f2h((float)fmin(fmax(rint((double)v.x * rinv), -128.0), 127.0));
    u.y = f2h((float)fmin(fmax(rint((double)v.y * rinv), -128.0), 127.0));
    u.z = f2h((float)fmin(fmax(rint((double)v.z * rinv), -128.0), 127.0));
    u.w = f2h((float)fmin(fmax(rint((double)v.w * rinv), -128.0), 127.0));
    *(ushort4*)&xq[(size_t)i * 4] = u;
  }
}

// ------- weight prep: LDS-tiled transpose fp32->f16 (coalesced both sides) --
__global__ __launch_bounds__(256) void prep_weights_kernel(
    const float* __restrict__ Wq, const float* __restrict__ Wk,
    const float* __restrict__ Wv, const float* __restrict__ Wo,
    const float* __restrict__ bq, const float* __restrict__ bk,
    const float* __restrict__ bv,
    u16* __restrict__ Wcat, u16* __restrict__ Wot, float* __restrict__ bcat) {
  __shared__ float t[64][65];
  const int m = blockIdx.y;
  const float* src = (m == 0) ? Wq : (m == 1) ? Wk : (m == 2) ? Wv : Wo;
  u16* dst = (m == 3) ? Wot : (Wcat + (size_t)m * 768 * 768);
  const int tile = blockIdx.x;
  const int r0 = (tile / 12) * 64, c0 = (tile - (tile / 12) * 12) * 64;
  const int i = threadIdx.x >> 6, j = threadIdx.x & 63;
  #pragma unroll
  for (int it = 0; it < 16; ++it) {
    const int row = it * 4 + i;
    t[row][j] = src[(size_t)(r0 + row) * 768 + c0 + j];
  }
  __syncthreads();
  #pragma unroll
  for (int it = 0; it < 16; ++it) {
    const int row = it * 4 + i;
    dst[(size_t)(c0 + row) * 768 + r0 + j] = f2h(t[j][row]);
  }
  if (blockIdx.x == 0 && m == 0) {
    for (int k = threadIdx.x; k < 768; k += 256) {
      bcat[k] = bq[k];
      bcat[k + 768] = bk[k];
      bcat[k + 1536] = bv[k];
    }
  }
}

// ---------------- 128x128 GEMM, BK=32, 4 waves, 2-phase dbuf, XCD grid ------
template <int MODE>
__global__ __launch_bounds__(256, 4) void gemm128(
    const u16* __restrict__ A, const u16* __restrict__ Bt,
    const float* __restrict__ bias, const float* __restrict__ scale_p,
    u16* __restrict__ Oq, u16* __restrict__ Ok, u16* __restrict__ Ovt,
    float* __restrict__ Of) {
  __shared__ u16 S[4][4608];   // S[0..1]=A dbuf, S[2..3]=B dbuf; epi scratch
  const int K = 768, nk = 24;
  const int tid = threadIdx.x;
  const int w = tid >> 6, l = tid & 63;
  const int l15 = l & 15, lk = l >> 4;
  const int wr = w >> 1, wc = w & 1;
  const int bid = blockIdx.x;
  const int g = bid & 7, li = bid >> 3;
  const int tn = li >> 3, tm = g * 8 + (li & 7);
  f32x4 acc[4][4] = {};
  const int rA = tid >> 2;
  const int c8 = (tid & 3) * 8;
  const u16* gA = A + (size_t)(tm * 128 + rA) * K + c8;
  const u16* gB = Bt + (size_t)(tn * 128 + rA) * K + c8;
  {
    char* lA = (char*)S[0] + w * 1024;
    char* lB = (char*)S[2] + w * 1024;
    gload16(gA, lA);
    gload16(gA + (size_t)64 * K, lA + 4096);
    gload16(gB, lB);
    gload16(gB + (size_t)64 * K, lB + 4096);
  }
  __syncthreads();
  for (int kt = 0; kt < nk; ++kt) {
    const int buf = kt & 1;
    if (kt + 1 < nk) {
      const int k0 = (kt + 1) * 32;
      char* lA = (char*)S[buf ^ 1] + w * 1024;
      char* lB = (char*)S[2 + (buf ^ 1)] + w * 1024;
      gload16(gA + k0, lA);
      gload16(gA + k0 + (size_t)64 * K, lA + 4096);
      gload16(gB + k0, lB);
      gload16(gB + k0 + (size_t)64 * K, lB + 4096);
    }
    short8 af[4], bf[4];
    #pragma unroll
    for (int mi = 0; mi < 4; ++mi)
      af[mi] = *(const short8*)&S[buf][(wr * 64 + mi * 16 + l15) * 32 + lk * 8];
    #pragma unroll
    for (int ni = 0; ni < 4; ++ni)
      bf[ni] = *(const short8*)&S[2 + buf][(wc * 64 + ni * 16 + l15) * 32 + lk * 8];
    #pragma unroll
    for (int mi = 0; mi < 4; ++mi)
      #pragma unroll
      for (int ni = 0; ni < 4; ++ni)
        acc[mi][ni] = mfma16(af[mi], bf[ni], acc[mi][ni]);
    __syncthreads();
  }

  if (MODE == 1) {
    #pragma unroll
    for (int mi = 0; mi < 4; ++mi)
      #pragma unroll
      for (int ni = 0; ni < 4; ++ni)
        #pragma unroll
        for (int j = 0; j < 4; ++j) {
          const int gm = tm * 128 + wr * 64 + mi * 16 + lk * 4 + j;
          const int c = tn * 128 + wc * 64 + ni * 16 + l15;
          Of[(size_t)gm * 768 + c] = acc[mi][ni][j] + bias[c];
        }
    return;
  }

  // MODE 0 epilogue: stage wave tile in LDS, store coalesced 128B rows.
  __syncthreads();
  const float s = *scale_p;
  const int seg = tn / 6;
  const int h = (tn - seg * 6) * 2 + wc;
  u16* esc = &S[w][0];
  #pragma unroll
  for (int mi = 0; mi < 4; ++mi) {
    #pragma unroll
    for (int ni = 0; ni < 4; ++ni) {
      #pragma unroll
      for (int j = 0; j < 4; ++j) {
        const float v = acc[mi][ni][j] * s + bias[tn * 128 + wc * 64 + ni * 16 + l15];
        const int row = mi * 16 + lk * 4 + j;
        const int col = ni * 16 + l15;
        if (seg < 2) esc[row * 72 + col] = f2h(v);
        else         esc[col * 72 + row] = f2h(v);
      }
    }
  }
  asm volatile("s_waitcnt lgkmcnt(0)" ::: "memory");
  const int n0 = tm * 128 + wr * 64;
  const int b = n0 >> 10, nn = n0 & 1023;
  u16* outp = (seg == 0) ? Oq : (seg == 1) ? Ok : Ovt;
  #pragma unroll
  for (int it = 0; it < 8; ++it) {
    const int r = it * 8 + (l >> 3);
    const int cc = (l & 7) * 8;
    short8 vv = *(const short8*)&esc[r * 72 + cc];
    size_t o;
    if (seg < 2)
      o = (((size_t)b * 12 + h) * 1024 + nn + r) * 64 + cc;
    else
      o = (((size_t)b * 12 + h) * 64 + r) * 1024 + nn + cc;
    *(short8*)&outp[o] = vv;
  }
}

// ---------------- fused attention (barrier-free, L2-direct, 2-pass) ---------
// grid (96 bh, 8 qt), 512 threads = 8 independent waves; wave w owns q-rows
// qt*128+w*16..+15. No __syncthreads. K/V frags read direct from global
// (L2-resident: XCD = bh%8 stable, 12 bh x 256KB = 3MB < 4MB L2).
__global__ __launch_bounds__(512, 4) void attn_kernel(
    const u16* __restrict__ Q, const u16* __restrict__ K,
    const u16* __restrict__ Vt, u16* __restrict__ ctx) {
  __shared__ u16 Pw[8][16 * 40];   // 10 KB, wave-private P transpose buffers
  const int bh = blockIdx.x, qt = blockIdx.y;
  const int b = bh / 12, h = bh - b * 12;
  const int tid = threadIdx.x;
  const int w = tid >> 6, l = tid & 63;
  const int l15 = l & 15, lk = l >> 4;

  // Q A-fragments (16 q-rows x 64 d)
  const size_t qoff = ((size_t)bh * 1024 + qt * 128 + w * 16 + l15) * 64 + lk * 8;
  const short8 qa0 = *(const short8*)(Q + qoff);
  const short8 qa1 = *(const short8*)(Q + qoff + 32);

  // K B-frag base: key row = kb16*16 + l15, d = lk*8 (+32)
  const u16* Kb = K + (size_t)bh * 65536 + (size_t)l15 * 64 + lk * 8;
  // V B-frag base: d row = dt*16 + l15, k = kt*64 + ko*32 + lk*8
  const u16* Vb = Vt + (size_t)bh * 65536 + (size_t)l15 * 1024 + lk * 8;

  // ---- pass A: exact row max (no LDS, no barriers) ----
  f32x4 mx = {-3e38f, -3e38f, -3e38f, -3e38f};
  #pragma unroll 4
  for (int kb16 = 0; kb16 < 64; ++kb16) {
    const u16* kp = Kb + (size_t)kb16 * 1024;
    short8 k0 = *(const short8*)kp;
    short8 k1 = *(const short8*)(kp + 32);
    f32x4 sv = {0.f, 0.f, 0.f, 0.f};
    sv = mfma16(qa0, k0, sv);
    sv = mfma16(qa1, k1, sv);
    #pragma unroll
    for (int j = 0; j < 4; ++j) mx[j] = fmaxf(mx[j], sv[j]);
  }
  #pragma unroll
  for (int o = 1; o < 16; o <<= 1) {
    #pragma unroll
    for (int j = 0; j < 4; ++j) mx[j] = fmaxf(mx[j], __shfl_xor(mx[j], o));
  }
  f32x4 mz;
  #pragma unroll
  for (int j = 0; j < 4; ++j) mz[j] = mx[j] * LOG2E_F;

  // ---- pass B: recompute S, ITA softmax, PV ----
  f32x4 sum = {0.f, 0.f, 0.f, 0.f};
  f32x4 pv[4] = {};
  u16* const pw = Pw[w];
  for (int kt = 0; kt < 16; ++kt) {
    #pragma unroll
    for (int ko = 0; ko < 2; ++ko) {
      // V frags loaded early: latency hides under the softmax VALU below
      short8 vv[4];
      #pragma unroll
      for (int dt = 0; dt < 4; ++dt)
        vv[dt] = *(const short8*)(Vb + (size_t)dt * 16384 + kt * 64 + ko * 32);
      #pragma unroll
      for (int ks2 = 0; ks2 < 2; ++ks2) {
        const int kb16 = kt * 4 + ko * 2 + ks2;
        const u16* kp = Kb + (size_t)kb16 * 1024;
        short8 k0 = *(const short8*)kp;
        short8 k1 = *(const short8*)(kp + 32);
        f32x4 sv = {0.f, 0.f, 0.f, 0.f};
        sv = mfma16(qa0, k0, sv);
        sv = mfma16(qa1, k1, sv);
        #pragma unroll
        for (int j = 0; j < 4; ++j) {
          float z = sv[j] * LOG2E_F;
          float zz = z - mz[j];
          float zi = floorf(zz);
          float p = ldexpf(1.0f + (zz - zi), (int)zi);  // exact 2^zi*(1+zf)
          sum[j] += p;
          pw[(lk * 4 + j) * 40 + ks2 * 16 + l15] = f2h(p);
        }
      }
      asm volatile("s_waitcnt lgkmcnt(0)" ::: "memory");
      short8 pa = *(const short8*)&pw[l15 * 40 + lk * 8];
      #pragma unroll
      for (int dt = 0; dt < 4; ++dt)
        pv[dt] = mfma16(pa, vv[dt], pv[dt]);
    }
  }
  #pragma unroll
  for (int o = 1; o < 16; o <<= 1) {
    #pragma unroll
    for (int j = 0; j < 4; ++j) sum[j] += __shfl_xor(sum[j], o);
  }
  const int nrow = qt * 128 + w * 16 + lk * 4;
  #pragma unroll
  for (int dt = 0; dt < 4; ++dt) {
    #pragma unroll
    for (int j = 0; j < 4; ++j) {
      float v = pv[dt][j] / sum[j];
      ctx[((size_t)b * 1024 + nrow + j) * 768 + h * 64 + dt * 16 + l15] = f2h(v);
    }
  }
}

// ---------------- host ----------------
extern "C" void kernel_launch(void* const* d_in, const int* in_sizes, int n_in,
                              void* d_out, int out_size, void* d_ws, size_t ws_size,
                              hipStream_t stream) {
  const float* x  = (const float*)d_in[0];
  const float* Wq = (const float*)d_in[1];
  const float* bq = (const float*)d_in[2];
  const float* Wk = (const float*)d_in[3];
  const float* bk = (const float*)d_in[4];
  const float* Wv = (const float*)d_in[5];
  const float* bv = (const float*)d_in[6];
  const float* Wo = (const float*)d_in[7];
  const float* bo = (const float*)d_in[8];
  float* out = (float*)d_out;

  char* ws = (char*)d_ws;
  float* part  = (float*)ws;               // 1024 f32
  double* dsc  = (double*)(ws + 4096);     // {s, 1/s} f64
  float* dscf  = (float*)(ws + 4112);      // s f32
  float* bcat  = (float*)(ws + 8192);      // 2304 f32
  size_t off = 8192 + 16384;
  const size_t WB = (size_t)768 * 768;
  const size_t XB = (size_t)8192 * 768;
  u16* xq   = (u16*)(ws + off); off += XB * 2;
  u16* Wcat = (u16*)(ws + off); off += 3 * WB * 2;
  u16* Wot  = (u16*)(ws + off); off += WB * 2;
  u16* Qb   = (u16*)(ws + off); off += XB * 2;
  u16* Kb   = (u16*)(ws + off); off += XB * 2;
  u16* Vtb  = (u16*)(ws + off); off += XB * 2;
  u16* ctx  = xq;  // xq dead after gemm128<0>; attn runs after -> safe alias
  (void)ws_size; (void)in_sizes; (void)n_in; (void)out_size;

  const int n4 = (8 * 1024 * 768) / 4;
  amax_part_kernel<<<1024, 256, 0, stream>>>((const float4*)x, part, n4);
  amax_fin_kernel<<<1, 256, 0, stream>>>(part, dsc, dscf);
  quant_kernel<<<2048, 256, 0, stream>>>((const float4*)x, xq, dsc, n4);
  prep_weights_kernel<<<dim3(144, 4), 256, 0, stream>>>(
      Wq, Wk, Wv, Wo, bq, bk, bv, Wcat, Wot, bcat);
  gemm128<0><<<1152, 256, 0, stream>>>(xq, Wcat, bcat, dscf,
                                       Qb, Kb, Vtb, nullptr);
  attn_kernel<<<dim3(96, 8), 512, 0, stream>>>(Qb, Kb, Vtb, ctx);
  gemm128<1><<<384, 256, 0, stream>>>(ctx, Wot, bo, nullptr,
                                      nullptr, nullptr, nullptr, out);
}

// Round 10
// 148.706 us; speedup vs baseline: 2.2788x; 2.2788x over previous
//
#include <hip/hip_runtime.h>

// ITA Self-Attention QAT — round 10 (2-pass attn, 32 q-rows/wave)
// B=8, N=1024, E=768, P=768, H=12, D=64
//
// vs round 9 (FAILED 0.0146): ITA's PWL softmax f(z)=2^floor(z)(1+frac(z))
// is shift-invariant ONLY for integer shifts; online m starts at a
// non-integer offset from the true row max -> wrong fractional positions.
// Two-pass exact-max is mathematically forced. Reverted to round-7 attn
// (proven 76us, absmax 0.00195) and doubled per-wave q-tile:
//  - 32 q-rows/wave (2 row frags), 256 q-rows/block, grid (96,4)
//  - 2x MFMA+VALU per barrier/staged byte; V ds_reads shared across row frags
//  - LDS 52KB (K 16 + V 16 + Pw 20) -> 3 blocks/CU
// Per-row arithmetic order identical to round 7 -> bit-identical output.
// GEMMs + prolog unchanged from round 7.

typedef unsigned short u16;
typedef __attribute__((ext_vector_type(8))) short short8;
typedef __attribute__((ext_vector_type(8))) _Float16 half8;
typedef __attribute__((ext_vector_type(4))) float f32x4;

#define LOG2E_F 1.4426950408889634f

static __device__ __forceinline__ half8 s2h(short8 s) {
  union { short8 s; half8 h; } u; u.s = s; return u.h;
}
static __device__ __forceinline__ f32x4 mfma16(short8 a, short8 b, f32x4 c) {
  return __builtin_amdgcn_mfma_f32_16x16x32_f16(s2h(a), s2h(b), c, 0, 0, 0);
}
static __device__ __forceinline__ u16 f2h(float f) {
  union { _Float16 h; u16 u; } v; v.h = (_Float16)f; return v.u;
}
static __device__ __forceinline__ void gload16(const void* g, void* l) {
  __builtin_amdgcn_global_load_lds(
      (const __attribute__((address_space(1))) void*)g,
      (__attribute__((address_space(3))) void*)l, 16, 0, 0);
}

// ---------------- amax reduction ----------------
__global__ __launch_bounds__(256) void amax_part_kernel(
    const float4* __restrict__ x, float* __restrict__ part, int n4) {
  float m = 0.f;
  int i = blockIdx.x * 256 + threadIdx.x;
  const int stride = gridDim.x * 256;
  for (; i < n4; i += stride) {
    float4 v = x[i];
    m = fmaxf(m, fmaxf(fmaxf(fabsf(v.x), fabsf(v.y)),
                       fmaxf(fabsf(v.z), fabsf(v.w))));
  }
  #pragma unroll
  for (int o = 1; o < 64; o <<= 1) m = fmaxf(m, __shfl_xor(m, o));
  __shared__ float sw[4];
  if ((threadIdx.x & 63) == 0) sw[threadIdx.x >> 6] = m;
  __syncthreads();
  if (threadIdx.x == 0)
    part[blockIdx.x] = fmaxf(fmaxf(sw[0], sw[1]), fmaxf(sw[2], sw[3]));
}

__global__ __launch_bounds__(256) void amax_fin_kernel(
    const float* __restrict__ part, double* __restrict__ dsc,
    float* __restrict__ dscf) {
  const int t = threadIdx.x;
  float m = fmaxf(fmaxf(part[t], part[t + 256]),
                  fmaxf(part[t + 512], part[t + 768]));
  #pragma unroll
  for (int o = 1; o < 64; o <<= 1) m = fmaxf(m, __shfl_xor(m, o));
  __shared__ float sw[4];
  if ((t & 63) == 0) sw[t >> 6] = m;
  __syncthreads();
  if (t == 0) {
    double sd = (double)(fmaxf(fmaxf(sw[0], sw[1]), fmaxf(sw[2], sw[3]))) / 127.0;
    if (sd < 1e-8) sd = 1e-8;
    dsc[0] = sd;
    dsc[1] = 1.0 / sd;
    dscf[0] = (float)sd;
  }
}

// ---------------- quantize: xq = clip(rint(x/s),-128,127), exact in f16 -----
__global__ __launch_bounds__(256) void quant_kernel(
    const float4* __restrict__ x, u16* __restrict__ xq,
    const double* __restrict__ dsc, int n4) {
  const double rinv = dsc[1];
  int i = blockIdx.x * 256 + threadIdx.x;
  const int stride = gridDim.x * 256;
  for (; i < n4; i += stride) {
    float4 v = x[i];
    ushort4 u;
    u.x = f2h((float)fmin(fmax(rint((double)v.x * rinv), -128.0), 127.0));
    u.y = f2h((float)fmin(fmax(rint((double)v.y * rinv), -128.0), 127.0));
    u.z = f2h((float)fmin(fmax(rint((double)v.z * rinv), -128.0), 127.0));
    u.w = f2h((float)fmin(fmax(rint((double)v.w * rinv), -128.0), 127.0));
    *(ushort4*)&xq[(size_t)i * 4] = u;
  }
}

// ------- weight prep: LDS-tiled transpose fp32->f16 (coalesced both sides) --
__global__ __launch_bounds__(256) void prep_weights_kernel(
    const float* __restrict__ Wq, const float* __restrict__ Wk,
    const float* __restrict__ Wv, const float* __restrict__ Wo,
    const float* __restrict__ bq, const float* __restrict__ bk,
    const float* __restrict__ bv,
    u16* __restrict__ Wcat, u16* __restrict__ Wot, float* __restrict__ bcat) {
  __shared__ float t[64][65];
  const int m = blockIdx.y;
  const float* src = (m == 0) ? Wq : (m == 1) ? Wk : (m == 2) ? Wv : Wo;
  u16* dst = (m == 3) ? Wot : (Wcat + (size_t)m * 768 * 768);
  const int tile = blockIdx.x;
  const int r0 = (tile / 12) * 64, c0 = (tile - (tile / 12) * 12) * 64;
  const int i = threadIdx.x >> 6, j = threadIdx.x & 63;
  #pragma unroll
  for (int it = 0; it < 16; ++it) {
    const int row = it * 4 + i;
    t[row][j] = src[(size_t)(r0 + row) * 768 + c0 + j];
  }
  __syncthreads();
  #pragma unroll
  for (int it = 0; it < 16; ++it) {
    const int row = it * 4 + i;
    dst[(size_t)(c0 + row) * 768 + r0 + j] = f2h(t[j][row]);
  }
  if (blockIdx.x == 0 && m == 0) {
    for (int k = threadIdx.x; k < 768; k += 256) {
      bcat[k] = bq[k];
      bcat[k + 768] = bk[k];
      bcat[k + 1536] = bv[k];
    }
  }
}

// ---------------- 128x128 GEMM, BK=32, 4 waves, 2-phase dbuf, XCD grid ------
template <int MODE>
__global__ __launch_bounds__(256, 4) void gemm128(
    const u16* __restrict__ A, const u16* __restrict__ Bt,
    const float* __restrict__ bias, const float* __restrict__ scale_p,
    u16* __restrict__ Oq, u16* __restrict__ Ok, u16* __restrict__ Ovt,
    float* __restrict__ Of) {
  __shared__ u16 S[4][4608];   // S[0..1]=A dbuf, S[2..3]=B dbuf; epi scratch
  const int K = 768, nk = 24;
  const int tid = threadIdx.x;
  const int w = tid >> 6, l = tid & 63;
  const int l15 = l & 15, lk = l >> 4;
  const int wr = w >> 1, wc = w & 1;
  const int bid = blockIdx.x;
  const int g = bid & 7, li = bid >> 3;
  const int tn = li >> 3, tm = g * 8 + (li & 7);
  f32x4 acc[4][4] = {};
  const int rA = tid >> 2;
  const int c8 = (tid & 3) * 8;
  const u16* gA = A + (size_t)(tm * 128 + rA) * K + c8;
  const u16* gB = Bt + (size_t)(tn * 128 + rA) * K + c8;
  {
    char* lA = (char*)S[0] + w * 1024;
    char* lB = (char*)S[2] + w * 1024;
    gload16(gA, lA);
    gload16(gA + (size_t)64 * K, lA + 4096);
    gload16(gB, lB);
    gload16(gB + (size_t)64 * K, lB + 4096);
  }
  __syncthreads();
  for (int kt = 0; kt < nk; ++kt) {
    const int buf = kt & 1;
    if (kt + 1 < nk) {
      const int k0 = (kt + 1) * 32;
      char* lA = (char*)S[buf ^ 1] + w * 1024;
      char* lB = (char*)S[2 + (buf ^ 1)] + w * 1024;
      gload16(gA + k0, lA);
      gload16(gA + k0 + (size_t)64 * K, lA + 4096);
      gload16(gB + k0, lB);
      gload16(gB + k0 + (size_t)64 * K, lB + 4096);
    }
    short8 af[4], bf[4];
    #pragma unroll
    for (int mi = 0; mi < 4; ++mi)
      af[mi] = *(const short8*)&S[buf][(wr * 64 + mi * 16 + l15) * 32 + lk * 8];
    #pragma unroll
    for (int ni = 0; ni < 4; ++ni)
      bf[ni] = *(const short8*)&S[2 + buf][(wc * 64 + ni * 16 + l15) * 32 + lk * 8];
    #pragma unroll
    for (int mi = 0; mi < 4; ++mi)
      #pragma unroll
      for (int ni = 0; ni < 4; ++ni)
        acc[mi][ni] = mfma16(af[mi], bf[ni], acc[mi][ni]);
    __syncthreads();
  }

  if (MODE == 1) {
    #pragma unroll
    for (int mi = 0; mi < 4; ++mi)
      #pragma unroll
      for (int ni = 0; ni < 4; ++ni)
        #pragma unroll
        for (int j = 0; j < 4; ++j) {
          const int gm = tm * 128 + wr * 64 + mi * 16 + lk * 4 + j;
          const int c = tn * 128 + wc * 64 + ni * 16 + l15;
          Of[(size_t)gm * 768 + c] = acc[mi][ni][j] + bias[c];
        }
    return;
  }

  // MODE 0 epilogue: stage wave tile in LDS, store coalesced 128B rows.
  __syncthreads();
  const float s = *scale_p;
  const int seg = tn / 6;
  const int h = (tn - seg * 6) * 2 + wc;
  u16* esc = &S[w][0];
  #pragma unroll
  for (int mi = 0; mi < 4; ++mi) {
    #pragma unroll
    for (int ni = 0; ni < 4; ++ni) {
      #pragma unroll
      for (int j = 0; j < 4; ++j) {
        const float v = acc[mi][ni][j] * s + bias[tn * 128 + wc * 64 + ni * 16 + l15];
        const int row = mi * 16 + lk * 4 + j;
        const int col = ni * 16 + l15;
        if (seg < 2) esc[row * 72 + col] = f2h(v);
        else         esc[col * 72 + row] = f2h(v);
      }
    }
  }
  asm volatile("s_waitcnt lgkmcnt(0)" ::: "memory");
  const int n0 = tm * 128 + wr * 64;
  const int b = n0 >> 10, nn = n0 & 1023;
  u16* outp = (seg == 0) ? Oq : (seg == 1) ? Ok : Ovt;
  #pragma unroll
  for (int it = 0; it < 8; ++it) {
    const int r = it * 8 + (l >> 3);
    const int cc = (l & 7) * 8;
    short8 vv = *(const short8*)&esc[r * 72 + cc];
    size_t o;
    if (seg < 2)
      o = (((size_t)b * 12 + h) * 1024 + nn + r) * 64 + cc;
    else
      o = (((size_t)b * 12 + h) * 64 + r) * 1024 + nn + cc;
    *(short8*)&outp[o] = vv;
  }
}

// ---------------- fused attention (flash, 2-pass exact-max, 32 q/wave) ------
// grid (96 bh, 4 qt), 512 threads = 8 waves; wave w owns q-rows
// qt*256 + w*32 .. +31 (two 16-row frags). K/V staged to LDS (dbuf,
// pre-swizzled source). Pass A: exact row max. Pass B: recompute, ITA
// softmax, PV. Per-row arithmetic order identical to round 7.
__global__ __launch_bounds__(512, 4) void attn_kernel(
    const u16* __restrict__ Q, const u16* __restrict__ K,
    const u16* __restrict__ Vt, u16* __restrict__ ctx) {
  __shared__ u16 Ks[2][64 * 64];   // 16 KB
  __shared__ u16 Vs[2][64 * 64];   // 16 KB
  __shared__ u16 Pw[8][32 * 40];   // 20 KB, wave-private P transpose buffers
  const int bh = blockIdx.x, qt = blockIdx.y;
  const int b = bh / 12, h = bh - b * 12;
  const int tid = threadIdx.x;
  const int w = tid >> 6, l = tid & 63;
  const int l15 = l & 15, lk = l >> 4;
  const int xr = l15 & 7;

  // Q A-fragments: 2 row-frags x 2 k-halves
  short8 qa[2][2];
  #pragma unroll
  for (int rf = 0; rf < 2; ++rf) {
    const size_t qoff =
        ((size_t)bh * 1024 + qt * 256 + w * 32 + rf * 16 + l15) * 64 + lk * 8;
    qa[rf][0] = *(const short8*)(Q + qoff);
    qa[rf][1] = *(const short8*)(Q + qoff + 32);
  }

  const int srow = tid >> 3;                       // 0..63
  const int schunk = ((l & 7) ^ (srow & 7)) * 8;   // pre-swizzled source chunk
  const u16* Kg = K + ((size_t)bh * 1024 + srow) * 64 + schunk;
  const u16* Vg = Vt + ((size_t)bh * 64 + srow) * 1024 + schunk;
  u16* const ksd[2] = {&Ks[0][w * 512], &Ks[1][w * 512]};
  u16* const vsd[2] = {&Vs[0][w * 512], &Vs[1][w * 512]};

  // ---- pass A: exact row max ----
  f32x4 mx[2];
  #pragma unroll
  for (int rf = 0; rf < 2; ++rf)
    #pragma unroll
    for (int j = 0; j < 4; ++j) mx[rf][j] = -3e38f;
  gload16(Kg, ksd[0]);
  __syncthreads();
  for (int kt = 0; kt < 16; ++kt) {
    const int buf = kt & 1;
    if (kt < 15) gload16(Kg + (size_t)(kt + 1) * 4096, ksd[buf ^ 1]);
    const u16* kb = Ks[buf];
    #pragma unroll
    for (int ks = 0; ks < 4; ++ks) {
      short8 k0 = *(const short8*)&kb[(ks * 16 + l15) * 64 + ((lk ^ xr) * 8)];
      short8 k1 = *(const short8*)&kb[(ks * 16 + l15) * 64 + (((lk + 4) ^ xr) * 8)];
      #pragma unroll
      for (int rf = 0; rf < 2; ++rf) {
        f32x4 sv = {0.f, 0.f, 0.f, 0.f};
        sv = mfma16(qa[rf][0], k0, sv);
        sv = mfma16(qa[rf][1], k1, sv);
        #pragma unroll
        for (int j = 0; j < 4; ++j) mx[rf][j] = fmaxf(mx[rf][j], sv[j]);
      }
    }
    __syncthreads();
  }
  f32x4 mz[2];
  #pragma unroll
  for (int rf = 0; rf < 2; ++rf) {
    #pragma unroll
    for (int o = 1; o < 16; o <<= 1) {
      #pragma unroll
      for (int j = 0; j < 4; ++j)
        mx[rf][j] = fmaxf(mx[rf][j], __shfl_xor(mx[rf][j], o));
    }
    #pragma unroll
    for (int j = 0; j < 4; ++j) mz[rf][j] = mx[rf][j] * LOG2E_F;
  }

  // ---- pass B: recompute S, ITA softmax, PV ----
  f32x4 sum[2] = {};
  f32x4 pv[2][4] = {};
  u16* const pw = Pw[w];
  gload16(Kg, ksd[0]);
  gload16(Vg, vsd[0]);
  __syncthreads();
  for (int kt = 0; kt < 16; ++kt) {
    const int buf = kt & 1;
    if (kt < 15) {
      gload16(Kg + (size_t)(kt + 1) * 4096, ksd[buf ^ 1]);
      gload16(Vg + (size_t)(kt + 1) * 64, vsd[buf ^ 1]);
    }
    const u16* kb = Ks[buf];
    const u16* vb = Vs[buf];
    #pragma unroll
    for (int ko = 0; ko < 2; ++ko) {
      #pragma unroll
      for (int ks2 = 0; ks2 < 2; ++ks2) {
        const int ks = ko * 2 + ks2;
        short8 k0 = *(const short8*)&kb[(ks * 16 + l15) * 64 + ((lk ^ xr) * 8)];
        short8 k1 = *(const short8*)&kb[(ks * 16 + l15) * 64 + (((lk + 4) ^ xr) * 8)];
        #pragma unroll
        for (int rf = 0; rf < 2; ++rf) {
          f32x4 sv = {0.f, 0.f, 0.f, 0.f};
          sv = mfma16(qa[rf][0], k0, sv);
          sv = mfma16(qa[rf][1], k1, sv);
          #pragma unroll
          for (int j = 0; j < 4; ++j) {
            float z = sv[j] * LOG2E_F;
            float zz = z - mz[rf][j];
            float zi = floorf(zz);
            float p = ldexpf(1.0f + (zz - zi), (int)zi);  // exact 2^zi*(1+zf)
            sum[rf][j] += p;
            pw[(rf * 16 + lk * 4 + j) * 40 + ks2 * 16 + l15] = f2h(p);
          }
        }
      }
      asm volatile("s_waitcnt lgkmcnt(0)" ::: "memory");
      short8 pa0 = *(const short8*)&pw[l15 * 40 + lk * 8];
      short8 pa1 = *(const short8*)&pw[(16 + l15) * 40 + lk * 8];
      #pragma unroll
      for (int dt = 0; dt < 4; ++dt) {
        short8 vv = *(const short8*)&vb[(dt * 16 + l15) * 64 +
                                        (((lk + 4 * ko) ^ xr) * 8)];
        pv[0][dt] = mfma16(pa0, vv, pv[0][dt]);
        pv[1][dt] = mfma16(pa1, vv, pv[1][dt]);
      }
    }
    __syncthreads();
  }
  #pragma unroll
  for (int rf = 0; rf < 2; ++rf) {
    #pragma unroll
    for (int o = 1; o < 16; o <<= 1) {
      #pragma unroll
      for (int j = 0; j < 4; ++j) sum[rf][j] += __shfl_xor(sum[rf][j], o);
    }
    const int nrow = qt * 256 + w * 32 + rf * 16 + lk * 4;
    #pragma unroll
    for (int dt = 0; dt < 4; ++dt) {
      #pragma unroll
      for (int j = 0; j < 4; ++j) {
        float v = pv[rf][dt][j] / sum[rf][j];
        ctx[((size_t)b * 1024 + nrow + j) * 768 + h * 64 + dt * 16 + l15] =
            f2h(v);
      }
    }
  }
}

// ---------------- host ----------------
extern "C" void kernel_launch(void* const* d_in, const int* in_sizes, int n_in,
                              void* d_out, int out_size, void* d_ws, size_t ws_size,
                              hipStream_t stream) {
  const float* x  = (const float*)d_in[0];
  const float* Wq = (const float*)d_in[1];
  const float* bq = (const float*)d_in[2];
  const float* Wk = (const float*)d_in[3];
  const float* bk = (const float*)d_in[4];
  const float* Wv = (const float*)d_in[5];
  const float* bv = (const float*)d_in[6];
  const float* Wo = (const float*)d_in[7];
  const float* bo = (const float*)d_in[8];
  float* out = (float*)d_out;

  char* ws = (char*)d_ws;
  float* part  = (float*)ws;               // 1024 f32
  double* dsc  = (double*)(ws + 4096);     // {s, 1/s} f64
  float* dscf  = (float*)(ws + 4112);      // s f32
  float* bcat  = (float*)(ws + 8192);      // 2304 f32
  size_t off = 8192 + 16384;
  const size_t WB = (size_t)768 * 768;
  const size_t XB = (size_t)8192 * 768;
  u16* xq   = (u16*)(ws + off); off += XB * 2;
  u16* Wcat = (u16*)(ws + off); off += 3 * WB * 2;
  u16* Wot  = (u16*)(ws + off); off += WB * 2;
  u16* Qb   = (u16*)(ws + off); off += XB * 2;
  u16* Kb   = (u16*)(ws + off); off += XB * 2;
  u16* Vtb  = (u16*)(ws + off); off += XB * 2;
  u16* ctx  = xq;  // xq dead after gemm128<0>; attn runs after -> safe alias
  (void)ws_size; (void)in_sizes; (void)n_in; (void)out_size;

  const int n4 = (8 * 1024 * 768) / 4;
  amax_part_kernel<<<1024, 256, 0, stream>>>((const float4*)x, part, n4);
  amax_fin_kernel<<<1, 256, 0, stream>>>(part, dsc, dscf);
  quant_kernel<<<2048, 256, 0, stream>>>((const float4*)x, xq, dsc, n4);
  prep_weights_kernel<<<dim3(144, 4), 256, 0, stream>>>(
      Wq, Wk, Wv, Wo, bq, bk, bv, Wcat, Wot, bcat);
  gemm128<0><<<1152, 256, 0, stream>>>(xq, Wcat, bcat, dscf,
                                       Qb, Kb, Vtb, nullptr);
  attn_kernel<<<dim3(96, 4), 512, 0, stream>>>(Qb, Kb, Vtb, ctx);
  gemm128<1><<<384, 256, 0, stream>>>(ctx, Wot, bo, nullptr,
                                      nullptr, nullptr, nullptr, out);
}

// Round 11
// 144.389 us; speedup vs baseline: 2.3469x; 1.0299x over previous
//
#include <hip/hip_runtime.h>

// ITA Self-Attention QAT — round 11 (attn: 4-wave blocks, even 3-round grid)
// B=8, N=1024, E=768, P=768, H=12, D=64
//
// vs round 10 (148.7us, attn 76.4us): 32q/wave was +24%/unit but 384 blocks
// = 1.5 uneven dispatch rounds ate it (Occ 29%). Fix: 4-wave/256-thread
// blocks, 128 q/block -> grid (96,8)=768 blocks = exactly 3 even rounds,
// 3 blocks/CU (43KB LDS), 12 waves/CU to overlap the MFMA->softmax->LDS->PV
// chain; barriers sync 4 waves not 8. Per-row math order unchanged ->
// bit-identical output. GEMMs + prolog unchanged from round 7.

typedef unsigned short u16;
typedef __attribute__((ext_vector_type(8))) short short8;
typedef __attribute__((ext_vector_type(8))) _Float16 half8;
typedef __attribute__((ext_vector_type(4))) float f32x4;

#define LOG2E_F 1.4426950408889634f

static __device__ __forceinline__ half8 s2h(short8 s) {
  union { short8 s; half8 h; } u; u.s = s; return u.h;
}
static __device__ __forceinline__ f32x4 mfma16(short8 a, short8 b, f32x4 c) {
  return __builtin_amdgcn_mfma_f32_16x16x32_f16(s2h(a), s2h(b), c, 0, 0, 0);
}
static __device__ __forceinline__ u16 f2h(float f) {
  union { _Float16 h; u16 u; } v; v.h = (_Float16)f; return v.u;
}
static __device__ __forceinline__ void gload16(const void* g, void* l) {
  __builtin_amdgcn_global_load_lds(
      (const __attribute__((address_space(1))) void*)g,
      (__attribute__((address_space(3))) void*)l, 16, 0, 0);
}

// ---------------- amax reduction ----------------
__global__ __launch_bounds__(256) void amax_part_kernel(
    const float4* __restrict__ x, float* __restrict__ part, int n4) {
  float m = 0.f;
  int i = blockIdx.x * 256 + threadIdx.x;
  const int stride = gridDim.x * 256;
  for (; i < n4; i += stride) {
    float4 v = x[i];
    m = fmaxf(m, fmaxf(fmaxf(fabsf(v.x), fabsf(v.y)),
                       fmaxf(fabsf(v.z), fabsf(v.w))));
  }
  #pragma unroll
  for (int o = 1; o < 64; o <<= 1) m = fmaxf(m, __shfl_xor(m, o));
  __shared__ float sw[4];
  if ((threadIdx.x & 63) == 0) sw[threadIdx.x >> 6] = m;
  __syncthreads();
  if (threadIdx.x == 0)
    part[blockIdx.x] = fmaxf(fmaxf(sw[0], sw[1]), fmaxf(sw[2], sw[3]));
}

__global__ __launch_bounds__(256) void amax_fin_kernel(
    const float* __restrict__ part, double* __restrict__ dsc,
    float* __restrict__ dscf) {
  const int t = threadIdx.x;
  float m = fmaxf(fmaxf(part[t], part[t + 256]),
                  fmaxf(part[t + 512], part[t + 768]));
  #pragma unroll
  for (int o = 1; o < 64; o <<= 1) m = fmaxf(m, __shfl_xor(m, o));
  __shared__ float sw[4];
  if ((t & 63) == 0) sw[t >> 6] = m;
  __syncthreads();
  if (t == 0) {
    double sd = (double)(fmaxf(fmaxf(sw[0], sw[1]), fmaxf(sw[2], sw[3]))) / 127.0;
    if (sd < 1e-8) sd = 1e-8;
    dsc[0] = sd;
    dsc[1] = 1.0 / sd;
    dscf[0] = (float)sd;
  }
}

// ---------------- quantize: xq = clip(rint(x/s),-128,127), exact in f16 -----
__global__ __launch_bounds__(256) void quant_kernel(
    const float4* __restrict__ x, u16* __restrict__ xq,
    const double* __restrict__ dsc, int n4) {
  const double rinv = dsc[1];
  int i = blockIdx.x * 256 + threadIdx.x;
  const int stride = gridDim.x * 256;
  for (; i < n4; i += stride) {
    float4 v = x[i];
    ushort4 u;
    u.x = f2h((float)fmin(fmax(rint((double)v.x * rinv), -128.0), 127.0));
    u.y = f2h((float)fmin(fmax(rint((double)v.y * rinv), -128.0), 127.0));
    u.z = f2h((float)fmin(fmax(rint((double)v.z * rinv), -128.0), 127.0));
    u.w = f2h((float)fmin(fmax(rint((double)v.w * rinv), -128.0), 127.0));
    *(ushort4*)&xq[(size_t)i * 4] = u;
  }
}

// ------- weight prep: LDS-tiled transpose fp32->f16 (coalesced both sides) --
__global__ __launch_bounds__(256) void prep_weights_kernel(
    const float* __restrict__ Wq, const float* __restrict__ Wk,
    const float* __restrict__ Wv, const float* __restrict__ Wo,
    const float* __restrict__ bq, const float* __restrict__ bk,
    const float* __restrict__ bv,
    u16* __restrict__ Wcat, u16* __restrict__ Wot, float* __restrict__ bcat) {
  __shared__ float t[64][65];
  const int m = blockIdx.y;
  const float* src = (m == 0) ? Wq : (m == 1) ? Wk : (m == 2) ? Wv : Wo;
  u16* dst = (m == 3) ? Wot : (Wcat + (size_t)m * 768 * 768);
  const int tile = blockIdx.x;
  const int r0 = (tile / 12) * 64, c0 = (tile - (tile / 12) * 12) * 64;
  const int i = threadIdx.x >> 6, j = threadIdx.x & 63;
  #pragma unroll
  for (int it = 0; it < 16; ++it) {
    const int row = it * 4 + i;
    t[row][j] = src[(size_t)(r0 + row) * 768 + c0 + j];
  }
  __syncthreads();
  #pragma unroll
  for (int it = 0; it < 16; ++it) {
    const int row = it * 4 + i;
    dst[(size_t)(c0 + row) * 768 + r0 + j] = f2h(t[j][row]);
  }
  if (blockIdx.x == 0 && m == 0) {
    for (int k = threadIdx.x; k < 768; k += 256) {
      bcat[k] = bq[k];
      bcat[k + 768] = bk[k];
      bcat[k + 1536] = bv[k];
    }
  }
}

// ---------------- 128x128 GEMM, BK=32, 4 waves, 2-phase dbuf, XCD grid ------
template <int MODE>
__global__ __launch_bounds__(256, 4) void gemm128(
    const u16* __restrict__ A, const u16* __restrict__ Bt,
    const float* __restrict__ bias, const float* __restrict__ scale_p,
    u16* __restrict__ Oq, u16* __restrict__ Ok, u16* __restrict__ Ovt,
    float* __restrict__ Of) {
  __shared__ u16 S[4][4608];   // S[0..1]=A dbuf, S[2..3]=B dbuf; epi scratch
  const int K = 768, nk = 24;
  const int tid = threadIdx.x;
  const int w = tid >> 6, l = tid & 63;
  const int l15 = l & 15, lk = l >> 4;
  const int wr = w >> 1, wc = w & 1;
  const int bid = blockIdx.x;
  const int g = bid & 7, li = bid >> 3;
  const int tn = li >> 3, tm = g * 8 + (li & 7);
  f32x4 acc[4][4] = {};
  const int rA = tid >> 2;
  const int c8 = (tid & 3) * 8;
  const u16* gA = A + (size_t)(tm * 128 + rA) * K + c8;
  const u16* gB = Bt + (size_t)(tn * 128 + rA) * K + c8;
  {
    char* lA = (char*)S[0] + w * 1024;
    char* lB = (char*)S[2] + w * 1024;
    gload16(gA, lA);
    gload16(gA + (size_t)64 * K, lA + 4096);
    gload16(gB, lB);
    gload16(gB + (size_t)64 * K, lB + 4096);
  }
  __syncthreads();
  for (int kt = 0; kt < nk; ++kt) {
    const int buf = kt & 1;
    if (kt + 1 < nk) {
      const int k0 = (kt + 1) * 32;
      char* lA = (char*)S[buf ^ 1] + w * 1024;
      char* lB = (char*)S[2 + (buf ^ 1)] + w * 1024;
      gload16(gA + k0, lA);
      gload16(gA + k0 + (size_t)64 * K, lA + 4096);
      gload16(gB + k0, lB);
      gload16(gB + k0 + (size_t)64 * K, lB + 4096);
    }
    short8 af[4], bf[4];
    #pragma unroll
    for (int mi = 0; mi < 4; ++mi)
      af[mi] = *(const short8*)&S[buf][(wr * 64 + mi * 16 + l15) * 32 + lk * 8];
    #pragma unroll
    for (int ni = 0; ni < 4; ++ni)
      bf[ni] = *(const short8*)&S[2 + buf][(wc * 64 + ni * 16 + l15) * 32 + lk * 8];
    #pragma unroll
    for (int mi = 0; mi < 4; ++mi)
      #pragma unroll
      for (int ni = 0; ni < 4; ++ni)
        acc[mi][ni] = mfma16(af[mi], bf[ni], acc[mi][ni]);
    __syncthreads();
  }

  if (MODE == 1) {
    #pragma unroll
    for (int mi = 0; mi < 4; ++mi)
      #pragma unroll
      for (int ni = 0; ni < 4; ++ni)
        #pragma unroll
        for (int j = 0; j < 4; ++j) {
          const int gm = tm * 128 + wr * 64 + mi * 16 + lk * 4 + j;
          const int c = tn * 128 + wc * 64 + ni * 16 + l15;
          Of[(size_t)gm * 768 + c] = acc[mi][ni][j] + bias[c];
        }
    return;
  }

  // MODE 0 epilogue: stage wave tile in LDS, store coalesced 128B rows.
  __syncthreads();
  const float s = *scale_p;
  const int seg = tn / 6;
  const int h = (tn - seg * 6) * 2 + wc;
  u16* esc = &S[w][0];
  #pragma unroll
  for (int mi = 0; mi < 4; ++mi) {
    #pragma unroll
    for (int ni = 0; ni < 4; ++ni) {
      #pragma unroll
      for (int j = 0; j < 4; ++j) {
        const float v = acc[mi][ni][j] * s + bias[tn * 128 + wc * 64 + ni * 16 + l15];
        const int row = mi * 16 + lk * 4 + j;
        const int col = ni * 16 + l15;
        if (seg < 2) esc[row * 72 + col] = f2h(v);
        else         esc[col * 72 + row] = f2h(v);
      }
    }
  }
  asm volatile("s_waitcnt lgkmcnt(0)" ::: "memory");
  const int n0 = tm * 128 + wr * 64;
  const int b = n0 >> 10, nn = n0 & 1023;
  u16* outp = (seg == 0) ? Oq : (seg == 1) ? Ok : Ovt;
  #pragma unroll
  for (int it = 0; it < 8; ++it) {
    const int r = it * 8 + (l >> 3);
    const int cc = (l & 7) * 8;
    short8 vv = *(const short8*)&esc[r * 72 + cc];
    size_t o;
    if (seg < 2)
      o = (((size_t)b * 12 + h) * 1024 + nn + r) * 64 + cc;
    else
      o = (((size_t)b * 12 + h) * 64 + r) * 1024 + nn + cc;
    *(short8*)&outp[o] = vv;
  }
}

// ------ fused attention (flash, 2-pass exact-max, 32 q/wave, 4 waves) -------
// grid (96 bh, 8 qt), 256 threads = 4 waves; wave w owns q-rows
// qt*128 + w*32 .. +31 (two 16-row frags). K/V staged to LDS (dbuf,
// pre-swizzled source; each wave stages 2x1KB per tile). 768 blocks =
// 3 even dispatch rounds, 3 blocks/CU.
__global__ __launch_bounds__(256, 3) void attn_kernel(
    const u16* __restrict__ Q, const u16* __restrict__ K,
    const u16* __restrict__ Vt, u16* __restrict__ ctx) {
  __shared__ u16 Ks[2][64 * 64];   // 16 KB
  __shared__ u16 Vs[2][64 * 64];   // 16 KB
  __shared__ u16 Pw[4][32 * 40];   // 10 KB, wave-private P transpose buffers
  const int bh = blockIdx.x, qt = blockIdx.y;
  const int b = bh / 12, h = bh - b * 12;
  const int tid = threadIdx.x;
  const int w = tid >> 6, l = tid & 63;
  const int l15 = l & 15, lk = l >> 4;
  const int xr = l15 & 7;

  // Q A-fragments: 2 row-frags x 2 k-halves
  short8 qa[2][2];
  #pragma unroll
  for (int rf = 0; rf < 2; ++rf) {
    const size_t qoff =
        ((size_t)bh * 1024 + qt * 128 + w * 32 + rf * 16 + l15) * 64 + lk * 8;
    qa[rf][0] = *(const short8*)(Q + qoff);
    qa[rf][1] = *(const short8*)(Q + qoff + 32);
  }

  // staging: wave w covers rows w*16..w*16+15 in two 1KB issues (i=0: rows
  // w*16..+7, i=1: +8..+15); lane l -> row base + (l>>3), slot l&7,
  // source chunk (l&7)^(row&7) = (l&7)^(l>>3)  (w*16, i*8 are 0 mod 8)
  const int r8 = l >> 3;
  const int schunk = ((l & 7) ^ r8) * 8;
  const u16* Kg0 = K + ((size_t)bh * 1024 + w * 16 + r8) * 64 + schunk;
  const u16* Kg1 = Kg0 + 512;            // +8 rows
  const u16* Vg0 = Vt + ((size_t)bh * 64 + w * 16 + r8) * 1024 + schunk;
  const u16* Vg1 = Vg0 + 8192;           // +8 d-rows

  #define STAGE_K(buf, kt)                                            \
    {                                                                 \
      gload16(Kg0 + (size_t)(kt) * 4096, &Ks[buf][w * 1024]);         \
      gload16(Kg1 + (size_t)(kt) * 4096, &Ks[buf][w * 1024 + 512]);   \
    }
  #define STAGE_V(buf, kt)                                            \
    {                                                                 \
      gload16(Vg0 + (size_t)(kt) * 64, &Vs[buf][w * 1024]);           \
      gload16(Vg1 + (size_t)(kt) * 64, &Vs[buf][w * 1024 + 512]);     \
    }

  // ---- pass A: exact row max ----
  f32x4 mx[2];
  #pragma unroll
  for (int rf = 0; rf < 2; ++rf)
    #pragma unroll
    for (int j = 0; j < 4; ++j) mx[rf][j] = -3e38f;
  STAGE_K(0, 0)
  __syncthreads();
  for (int kt = 0; kt < 16; ++kt) {
    const int buf = kt & 1;
    if (kt < 15) STAGE_K(buf ^ 1, kt + 1)
    const u16* kb = Ks[buf];
    #pragma unroll
    for (int ks = 0; ks < 4; ++ks) {
      short8 k0 = *(const short8*)&kb[(ks * 16 + l15) * 64 + ((lk ^ xr) * 8)];
      short8 k1 = *(const short8*)&kb[(ks * 16 + l15) * 64 + (((lk + 4) ^ xr) * 8)];
      #pragma unroll
      for (int rf = 0; rf < 2; ++rf) {
        f32x4 sv = {0.f, 0.f, 0.f, 0.f};
        sv = mfma16(qa[rf][0], k0, sv);
        sv = mfma16(qa[rf][1], k1, sv);
        #pragma unroll
        for (int j = 0; j < 4; ++j) mx[rf][j] = fmaxf(mx[rf][j], sv[j]);
      }
    }
    __syncthreads();
  }
  f32x4 mz[2];
  #pragma unroll
  for (int rf = 0; rf < 2; ++rf) {
    #pragma unroll
    for (int o = 1; o < 16; o <<= 1) {
      #pragma unroll
      for (int j = 0; j < 4; ++j)
        mx[rf][j] = fmaxf(mx[rf][j], __shfl_xor(mx[rf][j], o));
    }
    #pragma unroll
    for (int j = 0; j < 4; ++j) mz[rf][j] = mx[rf][j] * LOG2E_F;
  }

  // ---- pass B: recompute S, ITA softmax, PV ----
  f32x4 sum[2] = {};
  f32x4 pv[2][4] = {};
  u16* const pw = Pw[w];
  STAGE_K(0, 0)
  STAGE_V(0, 0)
  __syncthreads();
  for (int kt = 0; kt < 16; ++kt) {
    const int buf = kt & 1;
    if (kt < 15) {
      STAGE_K(buf ^ 1, kt + 1)
      STAGE_V(buf ^ 1, kt + 1)
    }
    const u16* kb = Ks[buf];
    const u16* vb = Vs[buf];
    #pragma unroll
    for (int ko = 0; ko < 2; ++ko) {
      #pragma unroll
      for (int ks2 = 0; ks2 < 2; ++ks2) {
        const int ks = ko * 2 + ks2;
        short8 k0 = *(const short8*)&kb[(ks * 16 + l15) * 64 + ((lk ^ xr) * 8)];
        short8 k1 = *(const short8*)&kb[(ks * 16 + l15) * 64 + (((lk + 4) ^ xr) * 8)];
        #pragma unroll
        for (int rf = 0; rf < 2; ++rf) {
          f32x4 sv = {0.f, 0.f, 0.f, 0.f};
          sv = mfma16(qa[rf][0], k0, sv);
          sv = mfma16(qa[rf][1], k1, sv);
          #pragma unroll
          for (int j = 0; j < 4; ++j) {
            float z = sv[j] * LOG2E_F;
            float zz = z - mz[rf][j];
            float zi = floorf(zz);
            float p = ldexpf(1.0f + (zz - zi), (int)zi);  // exact 2^zi*(1+zf)
            sum[rf][j] += p;
            pw[(rf * 16 + lk * 4 + j) * 40 + ks2 * 16 + l15] = f2h(p);
          }
        }
      }
      asm volatile("s_waitcnt lgkmcnt(0)" ::: "memory");
      short8 pa0 = *(const short8*)&pw[l15 * 40 + lk * 8];
      short8 pa1 = *(const short8*)&pw[(16 + l15) * 40 + lk * 8];
      #pragma unroll
      for (int dt = 0; dt < 4; ++dt) {
        short8 vv = *(const short8*)&vb[(dt * 16 + l15) * 64 +
                                        (((lk + 4 * ko) ^ xr) * 8)];
        pv[0][dt] = mfma16(pa0, vv, pv[0][dt]);
        pv[1][dt] = mfma16(pa1, vv, pv[1][dt]);
      }
    }
    __syncthreads();
  }
  #undef STAGE_K
  #undef STAGE_V
  #pragma unroll
  for (int rf = 0; rf < 2; ++rf) {
    #pragma unroll
    for (int o = 1; o < 16; o <<= 1) {
      #pragma unroll
      for (int j = 0; j < 4; ++j) sum[rf][j] += __shfl_xor(sum[rf][j], o);
    }
    const int nrow = qt * 128 + w * 32 + rf * 16 + lk * 4;
    #pragma unroll
    for (int dt = 0; dt < 4; ++dt) {
      #pragma unroll
      for (int j = 0; j < 4; ++j) {
        float v = pv[rf][dt][j] / sum[rf][j];
        ctx[((size_t)b * 1024 + nrow + j) * 768 + h * 64 + dt * 16 + l15] =
            f2h(v);
      }
    }
  }
}

// ---------------- host ----------------
extern "C" void kernel_launch(void* const* d_in, const int* in_sizes, int n_in,
                              void* d_out, int out_size, void* d_ws, size_t ws_size,
                              hipStream_t stream) {
  const float* x  = (const float*)d_in[0];
  const float* Wq = (const float*)d_in[1];
  const float* bq = (const float*)d_in[2];
  const float* Wk = (const float*)d_in[3];
  const float* bk = (const float*)d_in[4];
  const float* Wv = (const float*)d_in[5];
  const float* bv = (const float*)d_in[6];
  const float* Wo = (const float*)d_in[7];
  const float* bo = (const float*)d_in[8];
  float* out = (float*)d_out;

  char* ws = (char*)d_ws;
  float* part  = (float*)ws;               // 1024 f32
  double* dsc  = (double*)(ws + 4096);     // {s, 1/s} f64
  float* dscf  = (float*)(ws + 4112);      // s f32
  float* bcat  = (float*)(ws + 8192);      // 2304 f32
  size_t off = 8192 + 16384;
  const size_t WB = (size_t)768 * 768;
  const size_t XB = (size_t)8192 * 768;
  u16* xq   = (u16*)(ws + off); off += XB * 2;
  u16* Wcat = (u16*)(ws + off); off += 3 * WB * 2;
  u16* Wot  = (u16*)(ws + off); off += WB * 2;
  u16* Qb   = (u16*)(ws + off); off += XB * 2;
  u16* Kb   = (u16*)(ws + off); off += XB * 2;
  u16* Vtb  = (u16*)(ws + off); off += XB * 2;
  u16* ctx  = xq;  // xq dead after gemm128<0>; attn runs after -> safe alias
  (void)ws_size; (void)in_sizes; (void)n_in; (void)out_size;

  const int n4 = (8 * 1024 * 768) / 4;
  amax_part_kernel<<<1024, 256, 0, stream>>>((const float4*)x, part, n4);
  amax_fin_kernel<<<1, 256, 0, stream>>>(part, dsc, dscf);
  quant_kernel<<<2048, 256, 0, stream>>>((const float4*)x, xq, dsc, n4);
  prep_weights_kernel<<<dim3(144, 4), 256, 0, stream>>>(
      Wq, Wk, Wv, Wo, bq, bk, bv, Wcat, Wot, bcat);
  gemm128<0><<<1152, 256, 0, stream>>>(xq, Wcat, bcat, dscf,
                                       Qb, Kb, Vtb, nullptr);
  attn_kernel<<<dim3(96, 8), 256, 0, stream>>>(Qb, Kb, Vtb, ctx);
  gemm128<1><<<384, 256, 0, stream>>>(ctx, Wot, bo, nullptr,
                                      nullptr, nullptr, nullptr, out);
}